// Round 1
// baseline (225.446 us; speedup 1.0000x reference)
//
#include <hip/hip_runtime.h>
#include <hip/hip_bf16.h>
#include <stdint.h>

typedef __bf16 bf16_t;
typedef __bf16 bf16x8 __attribute__((ext_vector_type(8)));
typedef __bf16 bf16x4_t __attribute__((ext_vector_type(4)));
typedef float f32x4 __attribute__((ext_vector_type(4)));

#define B_   2
#define H_   16
#define D_   64
#define LQ_  2048
#define LC_  2048
#define M_   1024

__device__ __forceinline__ void gload_lds16(const void* g, void* l) {
  __builtin_amdgcn_global_load_lds((__attribute__((address_space(1))) unsigned int*)(g),
                                   (__attribute__((address_space(3))) unsigned int*)(l),
                                   16, 0, 0);
}

// ---------------- fp32 -> bf16 elementwise (vectorized) ----------------
__global__ void cvt_bf16_kernel(const float* __restrict__ in, bf16_t* __restrict__ out, int n4) {
  int i = blockIdx.x * blockDim.x + threadIdx.x;
  if (i < n4) {
    const float4 f = ((const float4*)in)[i];
    bf16x4_t o4;
    o4[0] = (__bf16)f.x; o4[1] = (__bf16)f.y; o4[2] = (__bf16)f.z; o4[3] = (__bf16)f.w;
    ((bf16x4_t*)out)[i] = o4;
  }
}

// ---------------- transpose + convert weights: out[n][k] = in[k][n] ----------------
// kvperm: source col j = h*128 + d*2 + c  ->  dest row n' = h*128 + c*64 + d
__global__ void transpose_cvt_kernel(const float* __restrict__ in, bf16_t* __restrict__ out,
                                     int K, int N, int kvperm) {
  __shared__ float tile[32][33];
  const int n0 = blockIdx.x * 32, k0 = blockIdx.y * 32;
  const int tx = threadIdx.x & 31, ty = threadIdx.x >> 5;
  #pragma unroll
  for (int r = ty; r < 32; r += 8)
    tile[r][tx] = in[(size_t)(k0 + r) * N + (n0 + tx)];
  __syncthreads();
  #pragma unroll
  for (int r = ty; r < 32; r += 8) {
    const int n = n0 + r;
    const int orow = kvperm ? ((n & ~127) | ((n & 1) << 6) | ((n >> 1) & 63)) : n;
    out[(size_t)orow * K + (k0 + tx)] = (__bf16)tile[tx][r];
  }
}

// ---------------- GEMM: C[M,N] = A[M,K] @ Bt[N,K]^T, m97 structure ----------------
// EPI 0: q_s = (acc + bq[col]) * 0.125 -> bf16 [M][N]
// EPI 1: kv split: col = h*128 + c*64 + d; bias = bkv[h*128+d*2+c];
//        c==0 -> K [B,H,LC,D]; c==1 -> V^T [B,H,D,LC]
// EPI 2: out = acc + bout[col] -> f32 [M][N]
template <int EPI>
__global__ __launch_bounds__(256)
void gemm_bt_kernel(const bf16_t* __restrict__ A, const bf16_t* __restrict__ Bt,
                    const float* __restrict__ bias,
                    void* __restrict__ out0, void* __restrict__ out1,
                    int N, int K) {
  __shared__ __attribute__((aligned(16))) bf16_t ldsA[128 * 64];
  __shared__ __attribute__((aligned(16))) bf16_t ldsB[128 * 64];
  const int tid  = threadIdx.x;
  const int wave = tid >> 6, lane = tid & 63;
  const int m0 = blockIdx.y * 128, n0 = blockIdx.x * 128;
  const int wr = wave >> 1, wc = wave & 1;
  const int lrow = lane & 15, lk = (lane >> 4) * 8;
  const int srow = lane >> 3, scol = (lane & 7) * 8;

  f32x4 acc[4][4] = {};

  for (int k0 = 0; k0 < K; k0 += 64) {
    __syncthreads();
    #pragma unroll
    for (int i = 0; i < 4; ++i) {
      const int c = wave * 4 + i;
      const int row = c * 8 + srow;
      gload_lds16(A  + (size_t)(m0 + row) * K + (k0 + scol), ldsA + c * 512);
      gload_lds16(Bt + (size_t)(n0 + row) * K + (k0 + scol), ldsB + c * 512);
    }
    __syncthreads();
    #pragma unroll
    for (int ks = 0; ks < 2; ++ks) {
      bf16x8 af[4], bfv[4];
      #pragma unroll
      for (int mi = 0; mi < 4; ++mi)
        af[mi] = *(const bf16x8*)(ldsA + (wr * 64 + mi * 16 + lrow) * 64 + ks * 32 + lk);
      #pragma unroll
      for (int ni = 0; ni < 4; ++ni)
        bfv[ni] = *(const bf16x8*)(ldsB + (wc * 64 + ni * 16 + lrow) * 64 + ks * 32 + lk);
      #pragma unroll
      for (int mi = 0; mi < 4; ++mi)
        #pragma unroll
        for (int ni = 0; ni < 4; ++ni)
          acc[mi][ni] = __builtin_amdgcn_mfma_f32_16x16x32_bf16(af[mi], bfv[ni], acc[mi][ni], 0, 0, 0);
    }
  }

  #pragma unroll
  for (int mi = 0; mi < 4; ++mi) {
    const int rbase = m0 + wr * 64 + mi * 16 + (lane >> 4) * 4;
    #pragma unroll
    for (int ni = 0; ni < 4; ++ni) {
      const int col = n0 + wc * 64 + ni * 16 + lrow;
      if constexpr (EPI == 0) {
        const float bv = bias[col];
        #pragma unroll
        for (int j = 0; j < 4; ++j)
          ((bf16_t*)out0)[(size_t)(rbase + j) * N + col] = (__bf16)((acc[mi][ni][j] + bv) * 0.125f);
      } else if constexpr (EPI == 1) {
        const int hh = col >> 7, cbit = (col >> 6) & 1, d = col & 63;
        const float bv = bias[hh * 128 + d * 2 + cbit];
        #pragma unroll
        for (int j = 0; j < 4; ++j) {
          const int row = rbase + j;
          const int bi = row >> 11, lc = row & 2047;
          const float val = acc[mi][ni][j] + bv;
          if (cbit == 0)
            ((bf16_t*)out0)[((size_t)(bi * 16 + hh) * 2048 + lc) * 64 + d] = (__bf16)val;
          else
            ((bf16_t*)out1)[((size_t)(bi * 16 + hh) * 64 + d) * 2048 + lc] = (__bf16)val;
        }
      } else {
        const float bv = bias[col];
        #pragma unroll
        for (int j = 0; j < 4; ++j)
          ((float*)out0)[(size_t)(rbase + j) * N + col] = acc[mi][ni][j] + bv;
      }
    }
  }
}

// ---------------- flash attention ----------------
// q: [B*LQ][1024] bf16, pre-scaled by 1/8. k: [B,H,LC,64]. vt: [B,H,64,LC].
// o: [B*LQ][1024] bf16 (col = h*64 + d)
__global__ __launch_bounds__(256)
void attn_kernel(const bf16_t* __restrict__ q, const bf16_t* __restrict__ k,
                 const bf16_t* __restrict__ vt, bf16_t* __restrict__ o) {
  __shared__ __attribute__((aligned(16))) bf16_t Ksh[64][72];   // [lc][d]
  __shared__ __attribute__((aligned(16))) bf16_t Vsh[64][72];   // [d][lc]
  __shared__ __attribute__((aligned(16))) bf16_t Psh[4][16][72];

  const int tid  = threadIdx.x;
  const int wave = tid >> 6, lane = tid & 63;
  const int bh = blockIdx.y;             // b*16 + h
  const int b  = bh >> 4, h = bh & 15;
  const int q0 = blockIdx.x * 64;
  const int lrow = lane & 15, lk = (lane >> 4) * 8;

  bf16x8 qa[2];
  {
    const size_t qbase = (size_t)(b * LQ_ + q0 + wave * 16 + lrow) * 1024 + h * 64;
    qa[0] = *(const bf16x8*)(q + qbase + lk);
    qa[1] = *(const bf16x8*)(q + qbase + 32 + lk);
  }

  float m_run[4], l_run[4];
  #pragma unroll
  for (int j = 0; j < 4; ++j) { m_run[j] = -1e30f; l_run[j] = 0.f; }
  f32x4 oacc[4] = {};

  const bf16_t* kg = k  + (size_t)bh * LC_ * 64;
  const bf16_t* vg = vt + (size_t)bh * 64 * 2048;

  for (int lc0 = 0; lc0 < LC_; lc0 += 64) {
    __syncthreads();
    #pragma unroll
    for (int it = 0; it < 2; ++it) {
      const int idx = tid + it * 256;
      const int r = idx >> 3, c8 = (idx & 7) * 8;
      *(bf16x8*)&Ksh[r][c8] = *(const bf16x8*)(kg + (size_t)(lc0 + r) * 64 + c8);
      *(bf16x8*)&Vsh[r][c8] = *(const bf16x8*)(vg + (size_t)r * 2048 + lc0 + c8);
    }
    __syncthreads();

    // S = Q K^T (pre-scaled)
    f32x4 sacc[4] = {};
    #pragma unroll
    for (int ks = 0; ks < 2; ++ks) {
      #pragma unroll
      for (int ni = 0; ni < 4; ++ni) {
        bf16x8 kf = *(const bf16x8*)&Ksh[ni * 16 + lrow][ks * 32 + lk];
        sacc[ni] = __builtin_amdgcn_mfma_f32_16x16x32_bf16(qa[ks], kf, sacc[ni], 0, 0, 0);
      }
    }

    // online softmax (row stats: 16-lane-group shuffle reduce)
    float mnew[4], fac[4];
    #pragma unroll
    for (int j = 0; j < 4; ++j) {
      float pm = fmaxf(fmaxf(sacc[0][j], sacc[1][j]), fmaxf(sacc[2][j], sacc[3][j]));
      #pragma unroll
      for (int s = 1; s < 16; s <<= 1)
        pm = fmaxf(pm, __shfl_xor(pm, s, 64));
      mnew[j] = fmaxf(m_run[j], pm);
      fac[j] = __expf(m_run[j] - mnew[j]);
      m_run[j] = mnew[j];
    }
    float psum[4] = {0.f, 0.f, 0.f, 0.f};
    #pragma unroll
    for (int ni = 0; ni < 4; ++ni) {
      #pragma unroll
      for (int j = 0; j < 4; ++j) {
        const float p = __expf(sacc[ni][j] - mnew[j]);
        psum[j] += p;
        Psh[wave][(lane >> 4) * 4 + j][ni * 16 + lrow] = (__bf16)p;
      }
    }
    #pragma unroll
    for (int j = 0; j < 4; ++j) {
      #pragma unroll
      for (int s = 1; s < 16; s <<= 1)
        psum[j] += __shfl_xor(psum[j], s, 64);
      l_run[j] = l_run[j] * fac[j] + psum[j];
    }
    #pragma unroll
    for (int ni = 0; ni < 4; ++ni)
      #pragma unroll
      for (int j = 0; j < 4; ++j)
        oacc[ni][j] *= fac[j];

    asm volatile("" ::: "memory");  // order P writes before PV reads

    // O += P @ V
    #pragma unroll
    for (int ks = 0; ks < 2; ++ks) {
      bf16x8 pa = *(const bf16x8*)&Psh[wave][lrow][ks * 32 + lk];
      #pragma unroll
      for (int ni = 0; ni < 4; ++ni) {
        bf16x8 vb = *(const bf16x8*)&Vsh[ni * 16 + lrow][ks * 32 + lk];
        oacc[ni] = __builtin_amdgcn_mfma_f32_16x16x32_bf16(pa, vb, oacc[ni], 0, 0, 0);
      }
    }
  }

  #pragma unroll
  for (int j = 0; j < 4; ++j) {
    const float rl = 1.f / l_run[j];
    const int row = b * LQ_ + q0 + wave * 16 + (lane >> 4) * 4 + j;
    #pragma unroll
    for (int ni = 0; ni < 4; ++ni)
      o[(size_t)row * 1024 + h * 64 + ni * 16 + lrow] = (__bf16)(oacc[ni][j] * rl);
  }
}

extern "C" void kernel_launch(void* const* d_in, const int* in_sizes, int n_in,
                              void* d_out, int out_size, void* d_ws, size_t ws_size,
                              hipStream_t stream) {
  const float* query   = (const float*)d_in[0];
  const float* context = (const float*)d_in[1];
  const float* Wq      = (const float*)d_in[2];
  const float* bq      = (const float*)d_in[3];
  const float* Wkv     = (const float*)d_in[4];
  const float* bkv     = (const float*)d_in[5];
  const float* Wout    = (const float*)d_in[6];
  const float* bout    = (const float*)d_in[7];

  char* p = (char*)d_ws;
  bf16_t* queryb = (bf16_t*)p; p += (size_t)4096 * 1024 * 2;
  bf16_t* ctxb   = (bf16_t*)p; p += (size_t)4096 * 1024 * 2;
  bf16_t* Wq_t   = (bf16_t*)p; p += (size_t)1024 * 1024 * 2;
  bf16_t* Wkv_t  = (bf16_t*)p; p += (size_t)2048 * 1024 * 2;
  bf16_t* Wout_t = (bf16_t*)p; p += (size_t)1024 * 1024 * 2;
  bf16_t* q_s    = (bf16_t*)p; p += (size_t)4096 * 1024 * 2;
  bf16_t* k_s    = (bf16_t*)p; p += (size_t)4096 * 1024 * 2;
  bf16_t* v_t    = (bf16_t*)p; p += (size_t)4096 * 1024 * 2;
  bf16_t* attnb  = (bf16_t*)p; p += (size_t)4096 * 1024 * 2;
  if ((size_t)(p - (char*)d_ws) > ws_size) return;  // fail loudly

  cvt_bf16_kernel<<<4096, 256, 0, stream>>>(query, queryb, 4096 * 1024 / 4);
  cvt_bf16_kernel<<<4096, 256, 0, stream>>>(context, ctxb, 4096 * 1024 / 4);
  transpose_cvt_kernel<<<dim3(32, 32), 256, 0, stream>>>(Wq,   Wq_t,   1024, 1024, 0);
  transpose_cvt_kernel<<<dim3(64, 32), 256, 0, stream>>>(Wkv,  Wkv_t,  1024, 2048, 1);
  transpose_cvt_kernel<<<dim3(32, 32), 256, 0, stream>>>(Wout, Wout_t, 1024, 1024, 0);

  gemm_bt_kernel<0><<<dim3(8, 32),  256, 0, stream>>>(queryb, Wq_t,  bq,  q_s,  nullptr, 1024, 1024);
  gemm_bt_kernel<1><<<dim3(16, 32), 256, 0, stream>>>(ctxb,   Wkv_t, bkv, k_s,  v_t,     2048, 1024);
  attn_kernel<<<dim3(LQ_ / 64, B_ * H_), 256, 0, stream>>>(q_s, k_s, v_t, attnb);
  gemm_bt_kernel<2><<<dim3(8, 32),  256, 0, stream>>>(attnb,  Wout_t, bout, d_out, nullptr, 1024, 1024);
}